// Round 1
// baseline (277.341 us; speedup 1.0000x reference)
//
#include <hip/hip_runtime.h>

// ---------------- types / helpers ----------------
typedef __attribute__((ext_vector_type(8))) short short8;   // 8 bf16 = 4 VGPRs (MFMA A/B frag)
typedef __attribute__((ext_vector_type(4))) short short4v;
typedef __attribute__((ext_vector_type(4))) float f32x4;    // MFMA C/D frag

#define MFMA(a, b, c) __builtin_amdgcn_mfma_f32_16x16x32_bf16((a), (b), (c), 0, 0, 0)

__device__ __forceinline__ short f2bf(float f) {   // RNE float->bf16 (bit pattern as short)
    union { float f; unsigned u; } v; v.f = f;
    unsigned r = v.u + 0x7fffu + ((v.u >> 16) & 1u);
    return (short)(r >> 16);
}
__device__ __forceinline__ float bf2f(short s) {
    union { unsigned u; float f; } v; v.u = ((unsigned)(unsigned short)s) << 16; return v.f;
}

// ---------------- fp32 -> bf16 conversion (weights + states) ----------------
// 7 segments: E1,V1,E2,V2,F1,F2 -> dstw (contiguous), states -> dstx
struct ConvArgs { const float* src[7]; int end[7]; };  // end[] in float4 units, cumulative

__global__ __launch_bounds__(256) void convert_weights_kernel(ConvArgs a,
                                                              short* __restrict__ dstw,
                                                              short* __restrict__ dstx) {
    int i4 = blockIdx.x * 256 + threadIdx.x;           // exactly 2,156,800 float4s
    int seg = 0;
#pragma unroll
    for (int s = 0; s < 6; s++) seg += (i4 >= a.end[s]) ? 1 : 0;
    int base = (seg == 0) ? 0 : a.end[seg - 1];
    float4 v = ((const float4*)a.src[seg])[i4 - base];
    short4v o; o.x = f2bf(v.x); o.y = f2bf(v.y); o.z = f2bf(v.z); o.w = f2bf(v.w);
    short* dst = (seg == 6) ? (dstx + (size_t)(i4 - a.end[5]) * 4)
                            : (dstw + (size_t)i4 * 4);
    *(short4v*)dst = o;
}

// ---------------- precompute Gt = (Qw^T Kw)/sqrt(d) (bf16) and wvec = (qb^T Kw)/sqrt(d) ----------------
// Gt[f][e] = scale * sum_c Qw[c][e] * Kw[c][f]   (B-frag layout for t = se @ G^T)
// wvec[f]  = scale * sum_c qb[c]    * Kw[c][f]
// grid 64: blockIdx = s*32 + h*8 + fg;  256 threads: f = fg*16 + (tid>>4), e0 = (tid&15)*8
__global__ __launch_bounds__(256) void precompute_gt_kernel(
    const float* __restrict__ Q1w, const float* __restrict__ K1w, const float* __restrict__ Q1b,
    const float* __restrict__ Q2w, const float* __restrict__ K2w, const float* __restrict__ Q2b,
    short* __restrict__ gt, float* __restrict__ wvec) {
    const int s  = blockIdx.x >> 5;
    const int h  = (blockIdx.x >> 3) & 3;
    const int fg = blockIdx.x & 7;
    const float* Qw = (s ? Q2w : Q1w) + (size_t)h * 16384;
    const float* Kw = (s ? K2w : K1w) + (size_t)h * 16384;
    const float* qb = (s ? Q2b : Q1b) + h * 128;
    const int f  = fg * 16 + (threadIdx.x >> 4);
    const int e0 = (threadIdx.x & 15) * 8;
    float acc[8] = {0.f, 0.f, 0.f, 0.f, 0.f, 0.f, 0.f, 0.f};
    float accw = 0.f;
    for (int c = 0; c < 128; c++) {
        float kv = Kw[c * 128 + f];               // wave-uniform per 16 lanes -> broadcast
        accw = fmaf(qb[c], kv, accw);
        float4 a0 = *(const float4*)(Qw + c * 128 + e0);
        float4 a1 = *(const float4*)(Qw + c * 128 + e0 + 4);
        acc[0] = fmaf(kv, a0.x, acc[0]); acc[1] = fmaf(kv, a0.y, acc[1]);
        acc[2] = fmaf(kv, a0.z, acc[2]); acc[3] = fmaf(kv, a0.w, acc[3]);
        acc[4] = fmaf(kv, a1.x, acc[4]); acc[5] = fmaf(kv, a1.y, acc[5]);
        acc[6] = fmaf(kv, a1.z, acc[6]); acc[7] = fmaf(kv, a1.w, acc[7]);
    }
    const float scale = 0.08838834764831845f;     // 1/sqrt(128)
    short8 o = { f2bf(acc[0] * scale), f2bf(acc[1] * scale), f2bf(acc[2] * scale), f2bf(acc[3] * scale),
                 f2bf(acc[4] * scale), f2bf(acc[5] * scale), f2bf(acc[6] * scale), f2bf(acc[7] * scale) };
    *(short8*)(gt + ((size_t)((s * 4 + h) * 128 + f)) * 128 + e0) = o;
    if (e0 == 0) wvec[(s * 4 + h) * 128 + f] = accw * scale;
}

// ---------------- fused attention stage ----------------
// LDS layout (short offsets), 39,680 B total -> 4 blocks/CU.
//   A: T  [64][136] (W bf16 [64][72] overlays after logits)
//   B: SE [64][136]
//   C: VT [32][72]
//   D: cb [64] floats
// X is NOT staged: phase-1 A-frags read straight from global bf16 (L1/L2-resident).
#define KQ_LD  136
#define VT_LD  72
#define W_LD   72
#define OFF_T  0
#define OFF_SE 8704
#define OFF_VT 17408
#define OFF_CB 19712       // float[64] at byte 39424
#define OFF_W  0
#define SMEM_SHORTS 19840  // 39,680 B

template<int IN>
__global__ __launch_bounds__(256, 4) void attn_stage_kernel(
    const short* __restrict__ xin,                      // [512][64][IN] bf16
    const short* __restrict__ Ew, const float* __restrict__ Eb,   // Ew bf16 [4][128][IN]
    const short* __restrict__ Gt, const float* __restrict__ wvec, // [4][128][128] bf16, [4][128] f32
    const short* __restrict__ Vw, const float* __restrict__ Vb,   // [4][32][128]
    float* __restrict__ w_out,                          // [4][512][64][64] fp32
    short* __restrict__ x_out)                          // [512][64][128] bf16
{
    __shared__ short sm[SMEM_SHORTS];
    const int tid  = threadIdx.x;
    // XCD-affinity decode: the 4 h-blocks of one b share blockIdx%8 -> same XCD L2.
    const int b    = blockIdx.x & 511;
    const int h    = blockIdx.x >> 9;
    const int wv   = tid >> 6;          // wave 0..3
    const int lane = tid & 63;
    const int quad = lane >> 4;         // MFMA k-group / row-group
    const int l16  = lane & 15;         // MFMA m/n index
    constexpr int NK1 = IN / 32;        // phase-1 k-steps (8 or 4)

    const short* xb = xin + (size_t)b * 64 * IN;

    // ---- prefetch phase-1 B-frags (E weights) ----
    short8 ebf[NK1 * 2];
    {
        const short* ewh = Ew + (size_t)h * 128 * IN;
#pragma unroll
        for (int k0i = 0; k0i < NK1; k0i++)
#pragma unroll
            for (int j = 0; j < 2; j++)
                ebf[k0i * 2 + j] = *(const short8*)(ewh + (size_t)(wv * 32 + j * 16 + l16) * IN + k0i * 32 + quad * 8);
    }

    short8 gtf[8];   // G frags, prefetched during phase-1 epilogue

    // ---- Phase 1: se = leaky(X @ Ew^T + Eb)  [64x128], col-split: wave -> cols wv*32..+31 ----
    // A-frags straight from global bf16 (no LDS staging, no initial barrier).
    {
        f32x4 acc[4][2];
#pragma unroll
        for (int j = 0; j < 2; j++) {
            float bv = Eb[h * 128 + wv * 32 + j * 16 + l16];
            f32x4 c = {bv, bv, bv, bv};
#pragma unroll
            for (int i = 0; i < 4; i++) acc[i][j] = c;
        }
#pragma unroll
        for (int k0i = 0; k0i < NK1; k0i++) {
            short8 a[4];
#pragma unroll
            for (int i = 0; i < 4; i++)
                a[i] = *(const short8*)(xb + (size_t)(i * 16 + l16) * IN + k0i * 32 + quad * 8);
#pragma unroll
            for (int i = 0; i < 4; i++)
#pragma unroll
                for (int j = 0; j < 2; j++)
                    acc[i][j] = MFMA(a[i], ebf[k0i * 2 + j], acc[i][j]);
        }
        // hoisted prefetch: G frags fly during phase-1 epilogue + barrier (ebf now dead)
        {
            const short* gth = Gt + (size_t)h * 16384;
#pragma unroll
            for (int k0i = 0; k0i < 4; k0i++)
#pragma unroll
                for (int j = 0; j < 2; j++)
                    gtf[k0i * 2 + j] = *(const short8*)(gth + (size_t)(wv * 32 + j * 16 + l16) * 128 + k0i * 32 + quad * 8);
        }
        // C/D layout: col = n0 + l16, row = m0 + quad*4 + r
#pragma unroll
        for (int i = 0; i < 4; i++)
#pragma unroll
            for (int j = 0; j < 2; j++)
#pragma unroll
                for (int r = 0; r < 4; r++) {
                    float v = acc[i][j][r];
                    v = (v >= 0.f) ? v : 0.01f * v;
                    sm[OFF_SE + (i * 16 + quad * 4 + r) * KQ_LD + wv * 32 + j * 16 + l16] = f2bf(v);
                }
    }
    __syncthreads();   // se published

    // ---- Phase 2: t = se @ G^T (no bias; K-GEMM eliminated algebraically); v; cb ----
    {
        f32x4 tacc[4][2];
        f32x4 z = {0.f, 0.f, 0.f, 0.f};
#pragma unroll
        for (int i = 0; i < 4; i++)
#pragma unroll
            for (int j = 0; j < 2; j++) tacc[i][j] = z;
#pragma unroll
        for (int k0i = 0; k0i < 4; k0i++) {
            short8 a[4];
#pragma unroll
            for (int i = 0; i < 4; i++)
                a[i] = *(const short8*)&sm[OFF_SE + (i * 16 + l16) * KQ_LD + k0i * 32 + quad * 8];
#pragma unroll
            for (int i = 0; i < 4; i++)
#pragma unroll
                for (int j = 0; j < 2; j++)
                    tacc[i][j] = MFMA(a[i], gtf[k0i * 2 + j], tacc[i][j]);
        }
        // write T (frees tacc before v-loop)
#pragma unroll
        for (int i = 0; i < 4; i++)
#pragma unroll
            for (int j = 0; j < 2; j++)
#pragma unroll
                for (int r = 0; r < 4; r++)
                    sm[OFF_T + (i * 16 + quad * 4 + r) * KQ_LD + wv * 32 + j * 16 + l16] = f2bf(tacc[i][j][r]);

        // v = leaky(se @ Vw^T + Vb) [64x32]; wave -> rows (wv&1)*32..+31, cols (wv>>1)*16..+15
        const short* vwh = Vw + (size_t)h * 32 * 128;
        const int n0v = (wv >> 1) * 16, mrow = (wv & 1) * 32;
        short8 vbf[4];
#pragma unroll
        for (int k0i = 0; k0i < 4; k0i++)
            vbf[k0i] = *(const short8*)(vwh + (size_t)(n0v + l16) * 128 + k0i * 32 + quad * 8);
        float vb = Vb[h * 32 + n0v + l16];
        f32x4 vacc[2];
        vacc[0] = (f32x4){vb, vb, vb, vb}; vacc[1] = vacc[0];
#pragma unroll
        for (int k0i = 0; k0i < 4; k0i++) {
            short8 a0 = *(const short8*)&sm[OFF_SE + (mrow + l16) * KQ_LD + k0i * 32 + quad * 8];
            short8 a1 = *(const short8*)&sm[OFF_SE + (mrow + 16 + l16) * KQ_LD + k0i * 32 + quad * 8];
            vacc[0] = MFMA(a0, vbf[k0i], vacc[0]);
            vacc[1] = MFMA(a1, vbf[k0i], vacc[1]);
        }
        // write vT (leaky applied) into its own region (no overlay hazard now)
#pragma unroll
        for (int i = 0; i < 2; i++)
#pragma unroll
            for (int r = 0; r < 4; r++) {
                float v = vacc[i][r];
                v = (v >= 0.f) ? v : 0.01f * v;
                sm[OFF_VT + (n0v + l16) * VT_LD + mrow + i * 16 + quad * 4 + r] = f2bf(v);
            }

        // cb[j] = se_j . wvec  (column bias of logits; row-constant terms cancel in softmax)
        {
            const float* wvh = wvec + h * 128;
            const int row = wv * 16 + (lane >> 2);
            const int e0 = (lane & 3) * 32;
            float s = 0.f;
#pragma unroll
            for (int u = 0; u < 32; u += 8) {
                short8 sv = *(const short8*)&sm[OFF_SE + row * KQ_LD + e0 + u];
                float4 w0 = *(const float4*)(wvh + e0 + u);
                float4 w1 = *(const float4*)(wvh + e0 + u + 4);
                s = fmaf(bf2f(sv[0]), w0.x, s); s = fmaf(bf2f(sv[1]), w0.y, s);
                s = fmaf(bf2f(sv[2]), w0.z, s); s = fmaf(bf2f(sv[3]), w0.w, s);
                s = fmaf(bf2f(sv[4]), w1.x, s); s = fmaf(bf2f(sv[5]), w1.y, s);
                s = fmaf(bf2f(sv[6]), w1.z, s); s = fmaf(bf2f(sv[7]), w1.w, s);
            }
            s += __shfl_xor(s, 1, 4);
            s += __shfl_xor(s, 2, 4);
            if ((lane & 3) == 0) ((float*)&sm[OFF_CB])[row] = s;
        }
    }
    __syncthreads();   // T, VT, cb published

    // ---- Phase 3: logits = t @ se^T (pre-scaled); row-split: wave -> rows wv*16..+15 ----
    f32x4 lacc[4];
#pragma unroll
    for (int jj = 0; jj < 4; jj++) lacc[jj] = (f32x4){0.f, 0.f, 0.f, 0.f};
#pragma unroll
    for (int k0 = 0; k0 < 128; k0 += 32) {
        short8 a = *(const short8*)&sm[OFF_T + (wv * 16 + l16) * KQ_LD + k0 + quad * 8];
#pragma unroll
        for (int jj = 0; jj < 4; jj++) {
            short8 b8 = *(const short8*)&sm[OFF_SE + (jj * 16 + l16) * KQ_LD + k0 + quad * 8];
            lacc[jj] = MFMA(a, b8, lacc[jj]);
        }
    }
    __syncthreads();   // T dead: W (bf16) overlays it

    // ---- softmax (+cb) -> direct nontemporal w_out stores from registers + W bf16 to LDS ----
    {
        const float* cbf = (const float*)&sm[OFF_CB];
        float cbv[4];
#pragma unroll
        for (int jj = 0; jj < 4; jj++) cbv[jj] = cbf[jj * 16 + l16];
#pragma unroll
        for (int jj = 0; jj < 4; jj++)
#pragma unroll
            for (int r = 0; r < 4; r++) lacc[jj][r] += cbv[jj];

        float mx[4], inv[4];
#pragma unroll
        for (int r = 0; r < 4; r++) {
            float m = lacc[0][r];
#pragma unroll
            for (int jj = 1; jj < 4; jj++) m = fmaxf(m, lacc[jj][r]);
#pragma unroll
            for (int s = 1; s < 16; s <<= 1) m = fmaxf(m, __shfl_xor(m, s, 16));
            mx[r] = m;
        }
        float sum[4] = {0.f, 0.f, 0.f, 0.f};
#pragma unroll
        for (int jj = 0; jj < 4; jj++)
#pragma unroll
            for (int r = 0; r < 4; r++) {
                float e = __expf(lacc[jj][r] - mx[r]);   // scale pre-folded into Gt/wvec
                lacc[jj][r] = e; sum[r] += e;
            }
#pragma unroll
        for (int r = 0; r < 4; r++) {
#pragma unroll
            for (int s = 1; s < 16; s <<= 1) sum[r] += __shfl_xor(sum[r], s, 16);
            inv[r] = 1.0f / sum[r];
        }
        float* wbase = w_out + ((size_t)(h * 512 + b)) * 64 * 64;
#pragma unroll
        for (int r = 0; r < 4; r++) {
            int row = wv * 16 + quad * 4 + r;
#pragma unroll
            for (int jj = 0; jj < 4; jj++) {
                float wval = lacc[jj][r] * inv[r];
                sm[OFF_W + row * W_LD + jj * 16 + l16] = f2bf(wval);
                __builtin_nontemporal_store(wval, wbase + row * 64 + jj * 16 + l16);
            }
        }
    }
    __syncthreads();

    // ---- Phase 4: att = w @ v -> x_out (bf16). wave -> rows wv*16..+15, cols 0..31 ----
    {
        f32x4 aacc[2]; aacc[0] = (f32x4){0.f, 0.f, 0.f, 0.f}; aacc[1] = aacc[0];
#pragma unroll
        for (int k0 = 0; k0 < 64; k0 += 32) {
            short8 a = *(const short8*)&sm[OFF_W + (wv * 16 + l16) * W_LD + k0 + quad * 8];
#pragma unroll
            for (int j = 0; j < 2; j++) {
                short8 b8 = *(const short8*)&sm[OFF_VT + (j * 16 + l16) * VT_LD + k0 + quad * 8];
                aacc[j] = MFMA(a, b8, aacc[j]);
            }
        }
        short* xob = x_out + (size_t)b * 64 * 128;
#pragma unroll
        for (int j = 0; j < 2; j++)
#pragma unroll
            for (int r = 0; r < 4; r++)
                xob[(size_t)(wv * 16 + quad * 4 + r) * 128 + h * 32 + j * 16 + l16] = f2bf(aacc[j][r]);
    }
}

// ---------------- final MLP + softmax, MFMA version ----------------
#define H_LD 72
__global__ __launch_bounds__(256)
void final_mlp_mfma_kernel(const short* __restrict__ x2,    // [32768][128] bf16
                           const short* __restrict__ F1wb,  // [64][128] bf16
                           const float* __restrict__ F1b,   // [64]
                           const short* __restrict__ F2wb,  // [16][64] bf16
                           const float* __restrict__ F2b,   // [16]
                           float* __restrict__ policy)      // [32768][16]
{
    __shared__ short hsm[4][16 * H_LD];   // per-wave h tile [16 rows][64 cols]
    const int tid  = threadIdx.x;
    const int wv   = tid >> 6;
    const int lane = tid & 63;
    const int quad = lane >> 4;
    const int l16  = lane & 15;
    const int rowbase = blockIdx.x * 64 + wv * 16;

    short8 a[4];
    const short* xrow = x2 + (size_t)(rowbase + l16) * 128;
#pragma unroll
    for (int k = 0; k < 4; k++) a[k] = *(const short8*)(xrow + k * 32 + quad * 8);
    f32x4 acc[4];
#pragma unroll
    for (int j = 0; j < 4; j++) { float bv = F1b[j * 16 + l16]; acc[j] = (f32x4){bv, bv, bv, bv}; }
#pragma unroll
    for (int k = 0; k < 4; k++)
#pragma unroll
        for (int j = 0; j < 4; j++) {
            short8 b8 = *(const short8*)(F1wb + (size_t)(j * 16 + l16) * 128 + k * 32 + quad * 8);
            acc[j] = MFMA(a[k], b8, acc[j]);
        }
    short* hh = &hsm[wv][0];
#pragma unroll
    for (int j = 0; j < 4; j++)
#pragma unroll
        for (int r = 0; r < 4; r++) {
            float v = acc[j][r];
            v = (v >= 0.f) ? v : 0.01f * v;
            hh[(quad * 4 + r) * H_LD + j * 16 + l16] = f2bf(v);
        }
    __syncthreads();

    f32x4 lg;
    { float bv = F2b[l16]; lg = (f32x4){bv, bv, bv, bv}; }
#pragma unroll
    for (int k = 0; k < 2; k++) {
        short8 a2 = *(const short8*)(hh + l16 * H_LD + k * 32 + quad * 8);
        short8 b8 = *(const short8*)(F2wb + (size_t)l16 * 64 + k * 32 + quad * 8);
        lg = MFMA(a2, b8, lg);
    }
#pragma unroll
    for (int r = 0; r < 4; r++) {
        float m = lg[r];
        m = fmaxf(m, __shfl_xor(m, 1, 16));
        m = fmaxf(m, __shfl_xor(m, 2, 16));
        m = fmaxf(m, __shfl_xor(m, 4, 16));
        m = fmaxf(m, __shfl_xor(m, 8, 16));
        float e = __expf(lg[r] - m);
        float s = e;
        s += __shfl_xor(s, 1, 16);
        s += __shfl_xor(s, 2, 16);
        s += __shfl_xor(s, 4, 16);
        s += __shfl_xor(s, 8, 16);
        policy[(size_t)(rowbase + quad * 4 + r) * 16 + l16] = e / s;
    }
}

// ---------------- launcher ----------------
extern "C" void kernel_launch(void* const* d_in, const int* in_sizes, int n_in,
                              void* d_out, int out_size, void* d_ws, size_t ws_size,
                              hipStream_t stream) {
    const float* states = (const float*)d_in[0];
    const float* E1w = (const float*)d_in[1];  const float* E1b = (const float*)d_in[2];
    const float* K1w = (const float*)d_in[3];  const float* K1b = (const float*)d_in[4];
    const float* Q1w = (const float*)d_in[5];  const float* Q1b = (const float*)d_in[6];
    const float* V1w = (const float*)d_in[7];  const float* V1b = (const float*)d_in[8];
    const float* E2w = (const float*)d_in[9];  const float* E2b = (const float*)d_in[10];
    const float* K2w = (const float*)d_in[11]; const float* K2b = (const float*)d_in[12];
    const float* Q2w = (const float*)d_in[13]; const float* Q2b = (const float*)d_in[14];
    const float* V2w = (const float*)d_in[15]; const float* V2b = (const float*)d_in[16];
    const float* F1w = (const float*)d_in[17]; const float* F1b = (const float*)d_in[18];
    const float* F2w = (const float*)d_in[19]; const float* F2b = (const float*)d_in[20];
    (void)K1b; (void)K2b;   // K biases only enter via wvec (qb^T Kw); kb terms cancel in softmax

    float* out    = (float*)d_out;
    float* policy = out;                        // [512][64][16]
    float* w1     = out + 512 * 64 * 16;        // [4][512][64][64]
    float* w2     = w1 + 4 * 512 * 64 * 64;     // [4][512][64][64]

    // ws layout (shorts): x1b | xsb (states bf16; x2b aliases it after stage1) | wts | gt | wvec
    short* wsb = (short*)d_ws;
    short* x1b = wsb;                           // 4,194,304 shorts
    short* xsb = wsb + 4194304;                 // 8,388,608 shorts (states bf16)
    short* x2b = xsb;                           // alias: xsb dead once stage1 done
    short* wts = wsb + 12582912;                // 238,592 shorts of bf16 weights
    short* wE1 = wts;                // [4][128][256] = 131072
    short* wV1 = wts + 131072;       // [4][32][128]  = 16384
    short* wE2 = wts + 147456;       // [4][128][128] = 65536
    short* wV2 = wts + 212992;       // 16384
    short* wF1 = wts + 229376;       // 8192
    short* wF2 = wts + 237568;       // 1024
    short* gt  = wts + 238592;       // [8][128][128] = 131072 shorts
    float* wvec = (float*)(wts + 238592 + 131072);  // [8][128] fp32

    ConvArgs ca;
    ca.src[0] = E1w; ca.src[1] = V1w; ca.src[2] = E2w; ca.src[3] = V2w;
    ca.src[4] = F1w; ca.src[5] = F2w; ca.src[6] = states;
    ca.end[0] = 32768;  ca.end[1] = 36864;  ca.end[2] = 53248;  ca.end[3] = 57344;
    ca.end[4] = 59392;  ca.end[5] = 59648;  ca.end[6] = 2156800;
    convert_weights_kernel<<<8425, 256, 0, stream>>>(ca, wts, xsb);
    precompute_gt_kernel<<<64, 256, 0, stream>>>(Q1w, K1w, Q1b, Q2w, K2w, Q2b, gt, wvec);

    attn_stage_kernel<256><<<2048, 256, 0, stream>>>(
        xsb, wE1, E1b, gt, wvec, wV1, V1b, w1, x1b);
    attn_stage_kernel<128><<<2048, 256, 0, stream>>>(
        x1b, wE2, E2b, gt + 65536, wvec + 512, wV2, V2b, w2, x2b);
    final_mlp_mfma_kernel<<<512, 256, 0, stream>>>(x2b, wF1, F1b, wF2, F2b, policy);
}

// Round 3
// 233.114 us; speedup vs baseline: 1.1897x; 1.1897x over previous
//
#include <hip/hip_runtime.h>

// ---------------- types / helpers ----------------
typedef __attribute__((ext_vector_type(8))) short short8;   // 8 bf16 = 4 VGPRs (MFMA A/B frag)
typedef __attribute__((ext_vector_type(4))) short short4v;
typedef __attribute__((ext_vector_type(4))) float f32x4;    // MFMA C/D frag
typedef __attribute__((ext_vector_type(2))) unsigned uint2v;

#define MFMA(a, b, c) __builtin_amdgcn_mfma_f32_16x16x32_bf16((a), (b), (c), 0, 0, 0)

__device__ __forceinline__ short f2bf(float f) {   // RNE float->bf16 (bit pattern as short)
    union { float f; unsigned u; } v; v.f = f;
    unsigned r = v.u + 0x7fffu + ((v.u >> 16) & 1u);
    return (short)(r >> 16);
}
__device__ __forceinline__ float bf2f(short s) {
    union { unsigned u; float f; } v; v.u = ((unsigned)(unsigned short)s) << 16; return v.f;
}
// pack two floats -> 2 bf16 in one u32 (pure integer ops; provably correct)
__device__ __forceinline__ unsigned pkbf(float lo, float hi) {
    return (unsigned)(unsigned short)f2bf(lo) | ((unsigned)(unsigned short)f2bf(hi) << 16);
}
__device__ __forceinline__ float lrelu(float v) { return (v >= 0.f) ? v : 0.01f * v; }

// ---------------- weight fp32 -> bf16 conversion (once per launch) ----------------
// 6 segments: E1,V1,E2,V2,F1,F2 -> dstw contiguous (59,648 float4s total)
struct ConvArgs { const float* src[6]; int end[6]; };  // end[] in float4 units, cumulative

__global__ __launch_bounds__(256) void convert_weights_kernel(ConvArgs a, short* __restrict__ dstw) {
    int i4 = blockIdx.x * 256 + threadIdx.x;
    int seg = 0;
#pragma unroll
    for (int s = 0; s < 5; s++) seg += (i4 >= a.end[s]) ? 1 : 0;
    int base = (seg == 0) ? 0 : a.end[seg - 1];
    float4 v = ((const float4*)a.src[seg])[i4 - base];
    uint2v o = { pkbf(v.x, v.y), pkbf(v.z, v.w) };
    *(uint2v*)(dstw + (size_t)i4 * 4) = o;
}

// ---------------- precompute Gt = (Qw^T Kw)/sqrt(d) (bf16) and wvec = (qb^T Kw)/sqrt(d) ----------------
__global__ __launch_bounds__(256) void precompute_gt_kernel(
    const float* __restrict__ Q1w, const float* __restrict__ K1w, const float* __restrict__ Q1b,
    const float* __restrict__ Q2w, const float* __restrict__ K2w, const float* __restrict__ Q2b,
    short* __restrict__ gt, float* __restrict__ wvec) {
    const int s  = blockIdx.x >> 5;
    const int h  = (blockIdx.x >> 3) & 3;
    const int fg = blockIdx.x & 7;
    const float* Qw = (s ? Q2w : Q1w) + (size_t)h * 16384;
    const float* Kw = (s ? K2w : K1w) + (size_t)h * 16384;
    const float* qb = (s ? Q2b : Q1b) + h * 128;
    const int f  = fg * 16 + (threadIdx.x >> 4);
    const int e0 = (threadIdx.x & 15) * 8;
    float acc[8] = {0.f, 0.f, 0.f, 0.f, 0.f, 0.f, 0.f, 0.f};
    float accw = 0.f;
#pragma unroll 4
    for (int c = 0; c < 128; c++) {
        float kv = Kw[c * 128 + f];
        accw = fmaf(qb[c], kv, accw);
        float4 a0 = *(const float4*)(Qw + c * 128 + e0);
        float4 a1 = *(const float4*)(Qw + c * 128 + e0 + 4);
        acc[0] = fmaf(kv, a0.x, acc[0]); acc[1] = fmaf(kv, a0.y, acc[1]);
        acc[2] = fmaf(kv, a0.z, acc[2]); acc[3] = fmaf(kv, a0.w, acc[3]);
        acc[4] = fmaf(kv, a1.x, acc[4]); acc[5] = fmaf(kv, a1.y, acc[5]);
        acc[6] = fmaf(kv, a1.z, acc[6]); acc[7] = fmaf(kv, a1.w, acc[7]);
    }
    const float scale = 0.08838834764831845f;     // 1/sqrt(128)
    short8 o = { f2bf(acc[0] * scale), f2bf(acc[1] * scale), f2bf(acc[2] * scale), f2bf(acc[3] * scale),
                 f2bf(acc[4] * scale), f2bf(acc[5] * scale), f2bf(acc[6] * scale), f2bf(acc[7] * scale) };
    *(short8*)(gt + ((size_t)((s * 4 + h) * 128 + f)) * 128 + e0) = o;
    if (e0 == 0) wvec[(s * 4 + h) * 128 + f] = accw * scale;
}

// ---------------- fused attention stage ----------------
// All MFMAs operand-SWAPPED: mfma(Wfrag, Xfrag) so C/D's 4 consecutive regs span a
// contiguous LDS/global dim -> every epilogue is integer-pack + one 8B write.
// LDS regions (short offsets):
//   X  [64][IN+8]  at 0 (dead after phase 1; T/VT/CB overlay)
//   T  [64][136]   at 0        (W [64][72] overlays after logits)
//   VT [32][72]    at 8704
//   CB float[64]   at 11008
//   SE [64][136]   at max(64*(IN+8), 11136)
// stage1: 51,200 B -> 3 blocks/CU;  stage2: 39,680 B -> 4 blocks/CU.
template<int IN, bool XF32>
__global__ __launch_bounds__(256, XF32 ? 3 : 4) void attn_stage_kernel(
    const void* __restrict__ xin,                      // [512][64][IN] fp32 (stage1) or bf16 (stage2)
    const short* __restrict__ Ew, const float* __restrict__ Eb,   // Ew bf16 [4][128][IN]
    const short* __restrict__ Gt, const float* __restrict__ wvec, // [4][128][128] bf16, [4][128] f32
    const short* __restrict__ Vw, const float* __restrict__ Vb,   // [4][32][128]
    float* __restrict__ w_out,                          // [4][512][64][64] fp32
    short* __restrict__ x_out)                          // [512][64][128] bf16
{
    constexpr int XLD   = IN + 8;
    constexpr int OFF_X = 0;
    constexpr int OFF_T = 0;
    constexpr int OFF_VT = 8704;
    constexpr int OFF_CB = 11008;
    constexpr int OFF_W  = 0;
    constexpr int OFF_SE = (64 * XLD > 11136) ? 64 * XLD : 11136;
    __shared__ short sm[OFF_SE + 64 * 136];

    const int tid  = threadIdx.x;
    // XCD-affinity decode: the 4 h-blocks of one b share blockIdx%8 -> same XCD L2.
    const int b    = blockIdx.x & 511;
    const int h    = blockIdx.x >> 9;
    const int wv   = tid >> 6;          // wave 0..3
    const int lane = tid & 63;
    const int quad = lane >> 4;
    const int l16  = lane & 15;
    constexpr int NK1 = IN / 32;

    // ---- stage X tile into LDS (coalesced; converts on the fly for stage 1) ----
    if constexpr (XF32) {
        const float* xb = (const float*)xin + (size_t)b * 64 * IN;
#pragma unroll
        for (int r = 0; r < IN / 16; r++) {
            int f4 = tid + 256 * r;
            int row = f4 / (IN / 4), c4 = f4 % (IN / 4);
            float4 v = ((const float4*)xb)[f4];
            uint2v o = { pkbf(v.x, v.y), pkbf(v.z, v.w) };
            *(uint2v*)&sm[OFF_X + row * XLD + c4 * 4] = o;
        }
    } else {
        const short* xb = (const short*)xin + (size_t)b * 64 * IN;
#pragma unroll
        for (int r = 0; r < IN / 32; r++) {
            int f8 = tid + 256 * r;
            int row = f8 / (IN / 8), c8 = f8 % (IN / 8);
            short8 v = *(const short8*)(xb + (size_t)f8 * 8);
            *(short8*)&sm[OFF_X + row * XLD + c8 * 8] = v;
        }
    }

    // ---- prefetch phase-1 weight frags (A operand now: Ew rows) ----
    short8 ebf[NK1 * 2];
    {
        const short* ewh = Ew + (size_t)h * 128 * IN;
#pragma unroll
        for (int k0i = 0; k0i < NK1; k0i++)
#pragma unroll
            for (int j = 0; j < 2; j++)
                ebf[k0i * 2 + j] = *(const short8*)(ewh + (size_t)(wv * 32 + j * 16 + l16) * IN + k0i * 32 + quad * 8);
    }
    __syncthreads();

    short8 gtf[8];   // G frags, prefetched during phase-1 epilogue

    // ---- Phase 1 (swapped): C[e][n] = Ew x X^T; lane holds 4 consecutive e -> packed SE write ----
    {
        f32x4 acc[4][2];
#pragma unroll
        for (int j = 0; j < 2; j++) {
            f32x4 eb4 = *(const f32x4*)&Eb[h * 128 + wv * 32 + j * 16 + quad * 4];
#pragma unroll
            for (int i = 0; i < 4; i++) acc[i][j] = eb4;
        }
        __builtin_amdgcn_s_setprio(1);
#pragma unroll
        for (int k0i = 0; k0i < NK1; k0i++) {
            short8 x8[4];
#pragma unroll
            for (int i = 0; i < 4; i++)
                x8[i] = *(const short8*)&sm[OFF_X + (i * 16 + l16) * XLD + k0i * 32 + quad * 8];
#pragma unroll
            for (int i = 0; i < 4; i++)
#pragma unroll
                for (int j = 0; j < 2; j++)
                    acc[i][j] = MFMA(ebf[k0i * 2 + j], x8[i], acc[i][j]);
        }
        __builtin_amdgcn_s_setprio(0);
        // hoisted prefetch: G frags fly during epilogue + barrier (ebf now dead)
        {
            const short* gth = Gt + (size_t)h * 16384;
#pragma unroll
            for (int k0i = 0; k0i < 4; k0i++)
#pragma unroll
                for (int j = 0; j < 2; j++)
                    gtf[k0i * 2 + j] = *(const short8*)(gth + (size_t)(wv * 32 + j * 16 + l16) * 128 + k0i * 32 + quad * 8);
        }
        // SE[n][e]: n = i*16+l16, e = wv*32 + j*16 + quad*4 + r  (r contiguous)
#pragma unroll
        for (int i = 0; i < 4; i++)
#pragma unroll
            for (int j = 0; j < 2; j++) {
                uint2v o = { pkbf(lrelu(acc[i][j][0]), lrelu(acc[i][j][1])),
                             pkbf(lrelu(acc[i][j][2]), lrelu(acc[i][j][3])) };
                *(uint2v*)&sm[OFF_SE + (i * 16 + l16) * 136 + wv * 32 + j * 16 + quad * 4] = o;
            }
    }
    __syncthreads();   // SE published; X dead

    // ---- Phase 2: T = SE @ G^T (swapped); V (packed epilogue); cb ----
    {
        f32x4 tacc[4][2];
        f32x4 z = {0.f, 0.f, 0.f, 0.f};
#pragma unroll
        for (int i = 0; i < 4; i++)
#pragma unroll
            for (int j = 0; j < 2; j++) tacc[i][j] = z;
        __builtin_amdgcn_s_setprio(1);
#pragma unroll
        for (int k0i = 0; k0i < 4; k0i++) {
            short8 se8[4];
#pragma unroll
            for (int i = 0; i < 4; i++)
                se8[i] = *(const short8*)&sm[OFF_SE + (i * 16 + l16) * 136 + k0i * 32 + quad * 8];
#pragma unroll
            for (int i = 0; i < 4; i++)
#pragma unroll
                for (int j = 0; j < 2; j++)
                    tacc[i][j] = MFMA(gtf[k0i * 2 + j], se8[i], tacc[i][j]);
        }
        // T[n][f]: n = i*16+l16, f = wv*32 + j*16 + quad*4 + r
#pragma unroll
        for (int i = 0; i < 4; i++)
#pragma unroll
            for (int j = 0; j < 2; j++) {
                uint2v o = { pkbf(tacc[i][j][0], tacc[i][j][1]),
                             pkbf(tacc[i][j][2], tacc[i][j][3]) };
                *(uint2v*)&sm[OFF_T + (i * 16 + l16) * 136 + wv * 32 + j * 16 + quad * 4] = o;
            }

        // v = leaky(SE @ Vw^T + Vb): non-swapped already yields contiguous se-row dim in VT
        const short* vwh = Vw + (size_t)h * 32 * 128;
        const int n0v = (wv >> 1) * 16, mrow = (wv & 1) * 32;
        short8 vbf[4];
#pragma unroll
        for (int k0i = 0; k0i < 4; k0i++)
            vbf[k0i] = *(const short8*)(vwh + (size_t)(n0v + l16) * 128 + k0i * 32 + quad * 8);
        float vb = Vb[h * 32 + n0v + l16];
        f32x4 vacc[2];
        vacc[0] = (f32x4){vb, vb, vb, vb}; vacc[1] = vacc[0];
#pragma unroll
        for (int k0i = 0; k0i < 4; k0i++) {
            short8 a0 = *(const short8*)&sm[OFF_SE + (mrow + l16) * 136 + k0i * 32 + quad * 8];
            short8 a1 = *(const short8*)&sm[OFF_SE + (mrow + 16 + l16) * 136 + k0i * 32 + quad * 8];
            vacc[0] = MFMA(a0, vbf[k0i], vacc[0]);
            vacc[1] = MFMA(a1, vbf[k0i], vacc[1]);
        }
        __builtin_amdgcn_s_setprio(0);
        // VT[o][n]: o = n0v + l16, n = mrow + i*16 + quad*4 + r (contiguous)
#pragma unroll
        for (int i = 0; i < 2; i++) {
            uint2v o = { pkbf(lrelu(vacc[i][0]), lrelu(vacc[i][1])),
                         pkbf(lrelu(vacc[i][2]), lrelu(vacc[i][3])) };
            *(uint2v*)&sm[OFF_VT + (n0v + l16) * 72 + mrow + i * 16 + quad * 4] = o;
        }

        // cb[k] = SE_k . wvec  (logit column bias; row-constant terms cancel in softmax)
        {
            const float* wvh = wvec + h * 128;
            const int row = wv * 16 + (lane >> 2);
            const int e0 = (lane & 3) * 32;
            float s = 0.f;
#pragma unroll
            for (int u = 0; u < 32; u += 8) {
                short8 sv = *(const short8*)&sm[OFF_SE + row * 136 + e0 + u];
                float4 w0 = *(const float4*)(wvh + e0 + u);
                float4 w1 = *(const float4*)(wvh + e0 + u + 4);
                s = fmaf(bf2f(sv[0]), w0.x, s); s = fmaf(bf2f(sv[1]), w0.y, s);
                s = fmaf(bf2f(sv[2]), w0.z, s); s = fmaf(bf2f(sv[3]), w0.w, s);
                s = fmaf(bf2f(sv[4]), w1.x, s); s = fmaf(bf2f(sv[5]), w1.y, s);
                s = fmaf(bf2f(sv[6]), w1.z, s); s = fmaf(bf2f(sv[7]), w1.w, s);
            }
            s += __shfl_xor(s, 1, 4);
            s += __shfl_xor(s, 2, 4);
            if ((lane & 3) == 0) ((float*)&sm[OFF_CB])[row] = s;
        }
    }
    __syncthreads();   // T, VT, cb published

    // ---- Phase 3 (swapped): C[k][q]; lane owns ONE q-row (l16) with 16 k-values ----
    f32x4 lacc[4];
#pragma unroll
    for (int jj = 0; jj < 4; jj++) lacc[jj] = (f32x4){0.f, 0.f, 0.f, 0.f};
    __builtin_amdgcn_s_setprio(1);
#pragma unroll
    for (int k0 = 0; k0 < 128; k0 += 32) {
        short8 t8 = *(const short8*)&sm[OFF_T + (wv * 16 + l16) * 136 + k0 + quad * 8];
#pragma unroll
        for (int jj = 0; jj < 4; jj++) {
            short8 se8 = *(const short8*)&sm[OFF_SE + (jj * 16 + l16) * 136 + k0 + quad * 8];
            lacc[jj] = MFMA(se8, t8, lacc[jj]);
        }
    }
    __builtin_amdgcn_s_setprio(0);
    __syncthreads();   // T dead: W overlays

    // ---- softmax: per-lane row, 2 shfls per reduction; packed W + full-line NT w_out ----
    {
        const float* cbf = (const float*)&sm[OFF_CB];
#pragma unroll
        for (int jj = 0; jj < 4; jj++) {
            f32x4 cb4 = *(const f32x4*)&cbf[jj * 16 + quad * 4];
            lacc[jj] += cb4;
        }
        float m01 = fmaxf(fmaxf(lacc[0][0], lacc[0][1]), fmaxf(lacc[0][2], lacc[0][3]));
        float m23 = fmaxf(fmaxf(lacc[1][0], lacc[1][1]), fmaxf(lacc[1][2], lacc[1][3]));
        float m45 = fmaxf(fmaxf(lacc[2][0], lacc[2][1]), fmaxf(lacc[2][2], lacc[2][3]));
        float m67 = fmaxf(fmaxf(lacc[3][0], lacc[3][1]), fmaxf(lacc[3][2], lacc[3][3]));
        float m = fmaxf(fmaxf(m01, m23), fmaxf(m45, m67));
        m = fmaxf(m, __shfl_xor(m, 16, 64));
        m = fmaxf(m, __shfl_xor(m, 32, 64));
        float sum = 0.f;
#pragma unroll
        for (int jj = 0; jj < 4; jj++)
#pragma unroll
            for (int r = 0; r < 4; r++) {
                float e = __expf(lacc[jj][r] - m);   // scale pre-folded into Gt/wvec
                lacc[jj][r] = e; sum += e;
            }
        sum += __shfl_xor(sum, 16, 64);
        sum += __shfl_xor(sum, 32, 64);
        float inv = 1.0f / sum;
        float* wbase = w_out + ((size_t)(h * 512 + b)) * 4096 + (size_t)(wv * 16 + l16) * 64;
#pragma unroll
        for (int jj = 0; jj < 4; jj++) {
            f32x4 w4 = { lacc[jj][0] * inv, lacc[jj][1] * inv, lacc[jj][2] * inv, lacc[jj][3] * inv };
            uint2v o = { pkbf(w4[0], w4[1]), pkbf(w4[2], w4[3]) };
            *(uint2v*)&sm[OFF_W + (wv * 16 + l16) * 72 + jj * 16 + quad * 4] = o;
            __builtin_nontemporal_store(w4, (f32x4*)(wbase + jj * 16 + quad * 4));  // full 64B lines/instr
        }
    }
    __syncthreads();   // W published

    // ---- Phase 4 (swapped): att C[o][q]; packed 8B x_out stores ----
    {
        f32x4 aacc[2]; aacc[0] = (f32x4){0.f, 0.f, 0.f, 0.f}; aacc[1] = aacc[0];
#pragma unroll
        for (int k0 = 0; k0 < 64; k0 += 32) {
            short8 w8 = *(const short8*)&sm[OFF_W + (wv * 16 + l16) * 72 + k0 + quad * 8];
#pragma unroll
            for (int j = 0; j < 2; j++) {
                short8 v8 = *(const short8*)&sm[OFF_VT + (j * 16 + l16) * 72 + k0 + quad * 8];
                aacc[j] = MFMA(v8, w8, aacc[j]);
            }
        }
        short* xob = x_out + (size_t)b * 64 * 128 + (size_t)(wv * 16 + l16) * 128 + h * 32;
#pragma unroll
        for (int j = 0; j < 2; j++) {
            uint2v o = { pkbf(aacc[j][0], aacc[j][1]), pkbf(aacc[j][2], aacc[j][3]) };
            *(uint2v*)&xob[j * 16 + quad * 4] = o;
        }
    }
}

// ---------------- final MLP + softmax (swapped MFMAs, packed stores) ----------------
#define H_LD 72
__global__ __launch_bounds__(256)
void final_mlp_mfma_kernel(const short* __restrict__ x2,    // [32768][128] bf16
                           const short* __restrict__ F1wb,  // [64][128] bf16
                           const float* __restrict__ F1b,   // [64]
                           const short* __restrict__ F2wb,  // [16][64] bf16
                           const float* __restrict__ F2b,   // [16]
                           float* __restrict__ policy)      // [32768][16]
{
    __shared__ short hsm[4][16 * H_LD];   // per-wave h tile [16 rows][64 cols]
    const int tid  = threadIdx.x;
    const int wv   = tid >> 6;
    const int lane = tid & 63;
    const int quad = lane >> 4;
    const int l16  = lane & 15;
    const int rowbase = blockIdx.x * 64 + wv * 16;

    // F1 (swapped): C[o][row]; lane's 4 regs span contiguous o
    short8 a[4];
    const short* xrow = x2 + (size_t)(rowbase + l16) * 128;
#pragma unroll
    for (int k = 0; k < 4; k++) a[k] = *(const short8*)(xrow + k * 32 + quad * 8);
    f32x4 acc[4];
#pragma unroll
    for (int j = 0; j < 4; j++) acc[j] = *(const f32x4*)&F1b[j * 16 + quad * 4];
#pragma unroll
    for (int k = 0; k < 4; k++)
#pragma unroll
        for (int j = 0; j < 4; j++) {
            short8 b8 = *(const short8*)(F1wb + (size_t)(j * 16 + l16) * 128 + k * 32 + quad * 8);
            acc[j] = MFMA(b8, a[k], acc[j]);
        }
    short* hh = &hsm[wv][0];
#pragma unroll
    for (int j = 0; j < 4; j++) {
        uint2v o = { pkbf(lrelu(acc[j][0]), lrelu(acc[j][1])),
                     pkbf(lrelu(acc[j][2]), lrelu(acc[j][3])) };
        *(uint2v*)&hh[l16 * H_LD + j * 16 + quad * 4] = o;   // h[row=l16][o contiguous]
    }
    __syncthreads();

    // F2 (swapped): C[p][row]; lane holds 4 contiguous p for row l16
    f32x4 lg = *(const f32x4*)&F2b[quad * 4];
#pragma unroll
    for (int k = 0; k < 2; k++) {
        short8 a2 = *(const short8*)(hh + l16 * H_LD + k * 32 + quad * 8);
        short8 b2 = *(const short8*)(F2wb + (size_t)l16 * 64 + k * 32 + quad * 8);
        lg = MFMA(b2, a2, lg);
    }
    // softmax over p: 4 in-lane + across quads (same row at lanes l16, l16+16, ...)
    float m = fmaxf(fmaxf(lg[0], lg[1]), fmaxf(lg[2], lg[3]));
    m = fmaxf(m, __shfl_xor(m, 16, 64));
    m = fmaxf(m, __shfl_xor(m, 32, 64));
    f32x4 e;
    float s = 0.f;
#pragma unroll
    for (int r = 0; r < 4; r++) { e[r] = __expf(lg[r] - m); s += e[r]; }
    s += __shfl_xor(s, 16, 64);
    s += __shfl_xor(s, 32, 64);
    float inv = 1.0f / s;
    f32x4 p4 = { e[0] * inv, e[1] * inv, e[2] * inv, e[3] * inv };
    __builtin_nontemporal_store(p4, (f32x4*)&policy[(size_t)(rowbase + l16) * 16 + quad * 4]);  // full lines
}

// ---------------- launcher ----------------
extern "C" void kernel_launch(void* const* d_in, const int* in_sizes, int n_in,
                              void* d_out, int out_size, void* d_ws, size_t ws_size,
                              hipStream_t stream) {
    const float* states = (const float*)d_in[0];
    const float* E1w = (const float*)d_in[1];  const float* E1b = (const float*)d_in[2];
    const float* K1w = (const float*)d_in[3];  const float* K1b = (const float*)d_in[4];
    const float* Q1w = (const float*)d_in[5];  const float* Q1b = (const float*)d_in[6];
    const float* V1w = (const float*)d_in[7];  const float* V1b = (const float*)d_in[8];
    const float* E2w = (const float*)d_in[9];  const float* E2b = (const float*)d_in[10];
    const float* K2w = (const float*)d_in[11]; const float* K2b = (const float*)d_in[12];
    const float* Q2w = (const float*)d_in[13]; const float* Q2b = (const float*)d_in[14];
    const float* V2w = (const float*)d_in[15]; const float* V2b = (const float*)d_in[16];
    const float* F1w = (const float*)d_in[17]; const float* F1b = (const float*)d_in[18];
    const float* F2w = (const float*)d_in[19]; const float* F2b = (const float*)d_in[20];
    (void)K1b; (void)K2b;   // kb terms cancel in softmax; K bias enters only via wvec

    float* out    = (float*)d_out;
    float* policy = out;                        // [512][64][16]
    float* w1     = out + 512 * 64 * 16;        // [4][512][64][64]
    float* w2     = w1 + 4 * 512 * 64 * 64;     // [4][512][64][64]

    // ws layout (shorts): x1b | x2b | bf16 weights | gt | wvec
    short* wsb = (short*)d_ws;
    short* x1b = wsb;                           // [512][64][128] = 4,194,304 shorts
    short* x2b = wsb + 4194304;                 // [512][64][128]
    short* wts = wsb + 8388608;
    short* wE1 = wts;                // [4][128][256] = 131072
    short* wV1 = wts + 131072;       // [4][32][128]  = 16384
    short* wE2 = wts + 147456;       // [4][128][128] = 65536
    short* wV2 = wts + 212992;       // 16384
    short* wF1 = wts + 229376;       // 8192
    short* wF2 = wts + 237568;       // 1024
    short* gt  = wts + 238592;       // [8][128][128] = 131072 shorts
    float* wvec = (float*)(wts + 238592 + 131072);  // [8][128] fp32

    ConvArgs ca;
    ca.src[0] = E1w; ca.src[1] = V1w; ca.src[2] = E2w; ca.src[3] = V2w;
    ca.src[4] = F1w; ca.src[5] = F2w;
    ca.end[0] = 32768;  ca.end[1] = 36864;  ca.end[2] = 53248;  ca.end[3] = 57344;
    ca.end[4] = 59392;  ca.end[5] = 59648;
    convert_weights_kernel<<<233, 256, 0, stream>>>(ca, wts);
    precompute_gt_kernel<<<64, 256, 0, stream>>>(Q1w, K1w, Q1b, Q2w, K2w, Q2b, gt, wvec);

    attn_stage_kernel<256, true><<<2048, 256, 0, stream>>>(
        (const void*)states, wE1, E1b, gt, wvec, wV1, V1b, w1, x1b);
    attn_stage_kernel<128, false><<<2048, 256, 0, stream>>>(
        (const void*)x1b, wE2, E2b, gt + 65536, wvec + 512, wV2, V2b, w2, x2b);
    final_mlp_mfma_kernel<<<512, 256, 0, stream>>>(x2b, wF1, F1b, wF2, F2b, policy);
}